// Round 7
// baseline (295.732 us; speedup 1.0000x reference)
//
#include <hip/hip_runtime.h>

// SSIM fused, round 12: move the cross-lane traffic from the DS pipe to DPP.
//  - Round 10/11 post-mortem: three different structures all plateau at
//    ~120 us; L3-warm replay dispatches ALSO take 120 us (not memory-bound);
//    occupancy 2x did nothing (shared-resource saturation); VALUBusy 33%.
//    The invariant: ~1250 wave-steps/CU x 20 ds_bpermute epilogue = ~25k
//    wave64 crossbar ops on the ONE per-CU DS pipe ~= 95% DS busy at
//    ~11 cyc/op. ds_bpermute throughput is the structural bottleneck.
//  - Fix: DPP row_shl:N (VALU, per-SIMD, no DS) for the +1/+2/+3 neighbor
//    fetch. DPP only works within 16-lane rows -> each 16-lane row group
//    owns an independent 26-col span with 3 halo lanes (13/16 productive),
//    so every neighbor reference stays in-row. 20 bperm -> 20 v_mov_dpp.
//  - Also: NO waves_per_eu attribute (r11's (8,8) made the allocator
//    squeeze to 28 regs, hurting prefetch). Live state ~35 regs -> fits
//    any build's budget (good=128, bad=64) with room for the A/B/P/Q
//    prefetch ping-pong. Old row k-7 still re-read from global (L2-hit,
//    proven by r11's FETCH = 1.04 passes).
//  - Floors: VALU ~33 us, HBM ~45 us, DS ~0 -> target 55-70 us any build.
// Geometry: 16 x 1 x 1080 x 1920 fp32; VALID 7x7 -> 16 x 1074 x 1914.

constexpr int W_IN = 1920, H_IN = 1080;
constexpr int WOUT = W_IN - 6;    // 1914
constexpr int HOUT = H_IN - 6;    // 1074
constexpr int NBATCH = 16;
constexpr int RCOLS = 26;         // productive cols per 16-lane row (13 x 2)
constexpr int TW = 16 * RCOLS;    // 416 cols per block (4 waves x 4 rows)
constexpr int TH = 43;            // output rows per y-tile; NITER = 49
constexpr int NBX = 5, NBY = 25;  // 5*416=2080>=1914, 25*43=1075>=1074
constexpr int NBLK = NBX * NBY * NBATCH;  // 2000 ~= 7.8 blocks/CU

constexpr float C1f = 6.5025f;    // (0.01*255)^2
constexpr float C2f = 58.5225f;   // (0.03*255)^2
constexpr float INV49 = 1.0f / 49.0f;

// DPP row_shl:N -- lane i reads lane i+N within its 16-lane row (the
// __shfl_down direction; ROCm's shfl_down lowers to row_shl). bound_ctrl=1:
// out-of-row sources read as 0 (finite, and those lanes are masked anyway).
template <int CTRL>
__device__ __forceinline__ float dpp_shl(float v) {
  return __int_as_float(__builtin_amdgcn_update_dpp(
      0, __float_as_int(v), CTRL, 0xf, 0xf, true));
}
#define SHL1(v) dpp_shl<0x101>(v)
#define SHL2(v) dpp_shl<0x102>(v)
#define SHL3(v) dpp_shl<0x103>(v)

__global__ __attribute__((amdgpu_flat_work_group_size(256, 256)))
void ssim_kernel(const float* __restrict__ img1, const float* __restrict__ img2,
                 double* __restrict__ partial) {
  __shared__ float wsum[4];

  const int t = threadIdx.x;
  const int lane = t & 63;
  const int sub = lane & 15;                     // index within DPP row
  const int xr = blockIdx.x * TW + (t >> 4) * RCOLS;  // 16-lane-row col base
  const int y0 = blockIdx.y * TH;
  const size_t ib = (size_t)blockIdx.z * (size_t)(H_IN * W_IN);
  const float* __restrict__ p1 = img1 + ib;
  const float* __restrict__ p2 = img2 + ib;

  const int c0 = xr + 2 * sub;                   // own output col 0 (even)
  const int gcol = min(c0, W_IN - 2);            // clamped, 8B-aligned
  const bool pv = sub < 13;                      // productive lane in row
  const bool m0 = pv && (c0 + 0 < WOUT);
  const bool m1 = pv && (c0 + 1 < WOUT);

  // running vertical sums: 5 quantities x 2 cols (the ONLY carried state)
  float V1_0 = 0.f, V1_1 = 0.f;   // sum a
  float V2_0 = 0.f, V2_1 = 0.f;   // sum b
  float V3_0 = 0.f, V3_1 = 0.f;   // sum a*a
  float V4_0 = 0.f, V4_1 = 0.f;   // sum b*b
  float V5_0 = 0.f, V5_1 = 0.f;   // sum a*b
  float accv = 0.f;

  // new-row prefetch ping-pong (A/B), old-row ping-pong (P/Q)
  float2 Aa = *(const float2*)(p1 + (size_t)y0 * W_IN + gcol);
  float2 Ab = *(const float2*)(p2 + (size_t)y0 * W_IN + gcol);
  float2 Ba, Bb, Pa, Pb, Qa, Qb;
  int gyn = y0 + 1;   // next NEW input row to load (block-uniform -> SALU)
  int gyo = y0 + 1;   // next OLD input row to prefetch
  int oy = y0;        // output row counter

#define EPI1(VA, VB, VAA, VBB, VAB, MASK)                                   \
  {                                                                         \
    const float mu1 = (VA) * INV49, mu2 = (VB) * INV49;                     \
    const float mu1s = mu1 * mu1, mu2s = mu2 * mu2, mu12 = mu1 * mu2;       \
    const float sg1 = fmaf((VAA), INV49, -mu1s);                            \
    const float sg2 = fmaf((VBB), INV49, -mu2s);                            \
    const float sg12 = fmaf((VAB), INV49, -mu12);                           \
    const float v1 = fmaf(2.f, sg12, C2f);                                  \
    const float v2 = sg1 + sg2 + C2f;                                       \
    const float num = fmaf(2.f, mu12, C1f) * v1;                            \
    const float den = (mu1s + mu2s + C1f) * v2;                             \
    const float ss = num * __builtin_amdgcn_rcpf(den);                      \
    accv += (MASK) ? ss : 0.f;                                              \
  }

  // horizontal 7-tap for quantity Q via pair sums + 3x row_shl (all VALU):
  // own cols (c0,c1); +1 lane -> (c0+2,c0+3); +2 -> (c0+4,c0+5);
  // +3 -> (c0+6,c0+7).  h0 = cols c0..c0+6 ; h1 = cols c1..c1+6.
#define HQ(Q)                                                               \
    const float s1_##Q = SHL1(H##Q);                                        \
    const float s2_##Q = SHL2(H##Q);                                        \
    const float s3_##Q = SHL3(H##Q);                                        \
    const float f3_##Q = SHL3(V##Q##_0);                                    \
    const float sh_##Q = s1_##Q + s2_##Q;                                   \
    const float h0_##Q = (H##Q + sh_##Q) + f3_##Q;                          \
    const float h1_##Q = (V##Q##_1 + sh_##Q) + s3_##Q;

#define VUPD_ADD(CAa, CAb)                                                  \
    V1_0 += CAa.x;                   V1_1 += CAa.y;                         \
    V2_0 += CAb.x;                   V2_1 += CAb.y;                         \
    V3_0 = fmaf(CAa.x, CAa.x, V3_0); V3_1 = fmaf(CAa.y, CAa.y, V3_1);       \
    V4_0 = fmaf(CAb.x, CAb.x, V4_0); V4_1 = fmaf(CAb.y, CAb.y, V4_1);       \
    V5_0 = fmaf(CAa.x, CAb.x, V5_0); V5_1 = fmaf(CAa.y, CAb.y, V5_1);

#define VUPD_SUB(COa, COb)                                                  \
    V1_0 -= COa.x;                     V1_1 -= COa.y;                       \
    V2_0 -= COb.x;                     V2_1 -= COb.y;                       \
    V3_0 = fmaf(-COa.x, COa.x, V3_0);  V3_1 = fmaf(-COa.y, COa.y, V3_1);    \
    V4_0 = fmaf(-COb.x, COb.x, V4_0);  V4_1 = fmaf(-COb.y, COb.y, V4_1);    \
    V5_0 = fmaf(-COa.x, COb.x, V5_0);  V5_1 = fmaf(-COa.y, COb.y, V5_1);

#define DO_EPI_BLOCK                                                        \
    if (oy < HOUT) {                                                        \
      const float H1 = V1_0 + V1_1;                                         \
      const float H2 = V2_0 + V2_1;                                         \
      const float H3 = V3_0 + V3_1;                                         \
      const float H4 = V4_0 + V4_1;                                         \
      const float H5 = V5_0 + V5_1;                                         \
      HQ(1) HQ(2) HQ(3) HQ(4) HQ(5)                                         \
      EPI1(h0_1, h0_2, h0_3, h0_4, h0_5, m0)                                \
      EPI1(h1_1, h1_2, h1_3, h1_4, h1_5, m1)                                \
    }                                                                       \
    ++oy;

  // warm-up step: add new row only (rows y0..y0+6 have no row to retire)
#define STEPW(CAa, CAb, NAa, NAb, DO_EPI)                                   \
  {                                                                         \
    NAa = *(const float2*)(p1 + (size_t)gyn * W_IN + gcol);                 \
    NAb = *(const float2*)(p2 + (size_t)gyn * W_IN + gcol);                 \
    gyn = min(gyn + 1, H_IN - 1);                                           \
    VUPD_ADD(CAa, CAb)                                                      \
    if (DO_EPI) { DO_EPI_BLOCK }                                            \
  }

  // main step: prefetch next new row + next old row; add CA, retire CO.
  // Old row k-7 re-read from global: fetched 7 steps ago by this same wave
  // -> L2-resident (r11 measured FETCH = 1.04 input passes). Same min()
  // clamp sequence as when the row was added -> V stays exact.
#define STEPM(CAa, CAb, NAa, NAb, COa, COb, NOa, NOb)                       \
  {                                                                         \
    NAa = *(const float2*)(p1 + (size_t)gyn * W_IN + gcol);                 \
    NAb = *(const float2*)(p2 + (size_t)gyn * W_IN + gcol);                 \
    gyn = min(gyn + 1, H_IN - 1);                                           \
    {                                                                       \
      const int yo = min(gyo, H_IN - 1);                                    \
      NOa = *(const float2*)(p1 + (size_t)yo * W_IN + gcol);                \
      NOb = *(const float2*)(p2 + (size_t)yo * W_IN + gcol);                \
      ++gyo;                                                                \
    }                                                                       \
    VUPD_ADD(CAa, CAb)                                                      \
    VUPD_SUB(COa, COb)                                                      \
    DO_EPI_BLOCK                                                            \
  }

  // warm-up: rows y0..y0+6 (row k in A if k-y0 even); step 7 emits row y0
  STEPW(Aa, Ab, Ba, Bb, false)
  STEPW(Ba, Bb, Aa, Ab, false)
  STEPW(Aa, Ab, Ba, Bb, false)
  STEPW(Ba, Bb, Aa, Ab, false)
  STEPW(Aa, Ab, Ba, Bb, false)
  STEPW(Ba, Bb, Aa, Ab, false)
  STEPW(Aa, Ab, Ba, Bb, true)
  // old-row prologue: row y0 -> P (consumed by the first main step)
  Pa = *(const float2*)(p1 + (size_t)y0 * W_IN + gcol);
  Pb = *(const float2*)(p2 + (size_t)y0 * W_IN + gcol);
  // 21 pairs: steps 7..48 emit rows y0+1..y0+42 (43 outputs incl warm-up)
  for (int gp = 0; gp < 21; ++gp) {
    STEPM(Ba, Bb, Aa, Ab, Pa, Pb, Qa, Qb)
    STEPM(Aa, Ab, Ba, Bb, Qa, Qb, Pa, Pb)
  }
#undef STEPM
#undef STEPW
#undef DO_EPI_BLOCK
#undef VUPD_SUB
#undef VUPD_ADD
#undef HQ
#undef EPI1

  // block reduction: 64-wide shuffle -> LDS -> one double per block
#pragma unroll
  for (int off = 32; off > 0; off >>= 1) accv += __shfl_down(accv, off);
  if ((t & 63) == 0) wsum[t >> 6] = accv;
  __syncthreads();
  if (t == 0) {
    const int bid = blockIdx.x + NBX * (blockIdx.y + NBY * blockIdx.z);
    partial[bid] = (double)wsum[0] + (double)wsum[1] +
                   (double)wsum[2] + (double)wsum[3];
  }
}

__global__ __launch_bounds__(256)
void finalize_kernel(const double* __restrict__ partial,
                     float* __restrict__ out) {
  const int tid = threadIdx.x;
  double s = 0.0;
  for (int i = tid; i < NBLK; i += 256) s += partial[i];
#pragma unroll
  for (int off = 32; off > 0; off >>= 1) s += __shfl_down(s, off);
  __shared__ double ws[4];
  if ((tid & 63) == 0) ws[tid >> 6] = s;
  __syncthreads();
  if (tid == 0) {
    const double tot = ws[0] + ws[1] + ws[2] + ws[3];
    out[0] = (float)(tot / ((double)NBATCH * (double)HOUT * (double)WOUT));
  }
}

extern "C" void kernel_launch(void* const* d_in, const int* in_sizes, int n_in,
                              void* d_out, int out_size, void* d_ws, size_t ws_size,
                              hipStream_t stream) {
  const float* img1 = (const float*)d_in[0];
  const float* img2 = (const float*)d_in[1];
  // d_in[2] is the uniform 1/49 window -- baked into INV49.
  double* partial = (double*)d_ws;  // NBLK doubles, every slot written
  dim3 grid(NBX, NBY, NBATCH);      // 5 x 25 x 16 = 2000 blocks
  hipLaunchKernelGGL(ssim_kernel, grid, dim3(256), 0, stream, img1, img2,
                     partial);
  hipLaunchKernelGGL(finalize_kernel, dim3(1), dim3(256), 0, stream, partial,
                     (float*)d_out);
}